// Round 3
// baseline (2606.220 us; speedup 1.0000x reference)
//
#include <hip/hip_runtime.h>

// Problem constants (fixed-shape: B=8192, IN=1024, N=4096, K=409)
#define BATCH 8192
#define INF   1024
#define NF    4096
#define BN_EPS 1e-5

// ---------------------------------------------------------------------------
// Kernel 1: zero the f64 stats accumulators (2*4096 doubles)
// ---------------------------------------------------------------------------
__global__ void zero_ws(double* __restrict__ p) {
    p[blockIdx.x * 256 + threadIdx.x] = 0.0;
}

// ---------------------------------------------------------------------------
// Kernel 2: masked f32 GEMM with chunked f64 shadow accumulation.
// Y[r][n] = sum_i x[r][i]*W[n][i]*mask[n][i] + b[n]
// Tile 128x128, BK=16, 256 threads, 8x8 acc/thread (2x2 blocks of 4x4).
// Every Kc=32 (2 K-steps) the f32 acc is drained into an f64 shadow:
// per-element y error ~7.6e-8 -> column-stat noise safely below flip budget.
// ---------------------------------------------------------------------------
__global__ __launch_bounds__(256, 2) void gemm_mask_f32k(
    const float* __restrict__ X, const float* __restrict__ W,
    const int* __restrict__ Mk, const float* __restrict__ bias,
    float* __restrict__ Y)
{
    __shared__ float As[16][132];
    __shared__ float Bs[16][132];

    const int t  = threadIdx.x;
    const int tx = t & 15;           // col group
    const int ty = t >> 4;           // row group
    const int row0 = blockIdx.y * 128;
    const int col0 = blockIdx.x * 128;

    const int lr = t >> 1;           // 0..127 tile row for loads
    const int lk = (t & 1) * 8;      // 0 or 8

    const float* Xp = X + (size_t)(row0 + lr) * INF + lk;
    const float* Wp = W + (size_t)(col0 + lr) * INF + lk;
    const int*   Mp = Mk + (size_t)(col0 + lr) * INF + lk;

    float  acc[64];
    double sh[64];
#pragma unroll
    for (int q = 0; q < 64; ++q) { acc[q] = 0.0f; sh[q] = 0.0; }

    for (int k0 = 0; k0 < INF; k0 += 16) {
        const float4 a0 = *(const float4*)(Xp + k0);
        const float4 a1 = *(const float4*)(Xp + k0 + 4);
        float4 b0 = *(const float4*)(Wp + k0);
        float4 b1 = *(const float4*)(Wp + k0 + 4);
        const int4 m0 = *(const int4*)(Mp + k0);
        const int4 m1 = *(const int4*)(Mp + k0 + 4);
        b0.x *= (float)m0.x; b0.y *= (float)m0.y;
        b0.z *= (float)m0.z; b0.w *= (float)m0.w;
        b1.x *= (float)m1.x; b1.y *= (float)m1.y;
        b1.z *= (float)m1.z; b1.w *= (float)m1.w;

        __syncthreads();   // protect previous iteration's LDS reads
        As[lk + 0][lr] = a0.x; As[lk + 1][lr] = a0.y;
        As[lk + 2][lr] = a0.z; As[lk + 3][lr] = a0.w;
        As[lk + 4][lr] = a1.x; As[lk + 5][lr] = a1.y;
        As[lk + 6][lr] = a1.z; As[lk + 7][lr] = a1.w;
        Bs[lk + 0][lr] = b0.x; Bs[lk + 1][lr] = b0.y;
        Bs[lk + 2][lr] = b0.z; Bs[lk + 3][lr] = b0.w;
        Bs[lk + 4][lr] = b1.x; Bs[lk + 5][lr] = b1.y;
        Bs[lk + 6][lr] = b1.z; Bs[lk + 7][lr] = b1.w;
        __syncthreads();

#pragma unroll
        for (int kk = 0; kk < 16; ++kk) {
            const float4 a0v = *(const float4*)&As[kk][ty * 4];
            const float4 a1v = *(const float4*)&As[kk][64 + ty * 4];
            const float4 b0v = *(const float4*)&Bs[kk][tx * 4];
            const float4 b1v = *(const float4*)&Bs[kk][64 + tx * 4];
            const float av[8] = {a0v.x, a0v.y, a0v.z, a0v.w, a1v.x, a1v.y, a1v.z, a1v.w};
            const float bv[8] = {b0v.x, b0v.y, b0v.z, b0v.w, b1v.x, b1v.y, b1v.z, b1v.w};
#pragma unroll
            for (int i = 0; i < 8; ++i)
#pragma unroll
                for (int j = 0; j < 8; ++j)
                    acc[i * 8 + j] = fmaf(av[i], bv[j], acc[i * 8 + j]);
        }

        if (k0 & 16) {   // drain f32 chunk (Kc=32) into f64 shadow
#pragma unroll
            for (int q = 0; q < 64; ++q) { sh[q] += (double)acc[q]; acc[q] = 0.0f; }
        }
    }

    // epilogue: add bias in f64, store f32
#pragma unroll
    for (int i = 0; i < 8; ++i) {
        const int row = row0 + (i >> 2) * 64 + ty * 4 + (i & 3);
#pragma unroll
        for (int jb = 0; jb < 2; ++jb) {
            const int col = col0 + jb * 64 + tx * 4;
            float4 o;
            o.x = (float)(sh[i * 8 + jb * 4 + 0] + (double)bias[col + 0]);
            o.y = (float)(sh[i * 8 + jb * 4 + 1] + (double)bias[col + 1]);
            o.z = (float)(sh[i * 8 + jb * 4 + 2] + (double)bias[col + 2]);
            o.w = (float)(sh[i * 8 + jb * 4 + 3] + (double)bias[col + 3]);
            *(float4*)&Y[(size_t)row * NF + col] = o;
        }
    }
}

// ---------------------------------------------------------------------------
// Kernel 3: per-column partial sums (f64) over 256-row chunks
// ---------------------------------------------------------------------------
__global__ __launch_bounds__(256) void stats_partial(
    const float* __restrict__ Y, double* __restrict__ dsum, double* __restrict__ dsqs)
{
    const int col = blockIdx.x * 256 + threadIdx.x;
    const int r0  = blockIdx.y * 256;
    double s = 0.0, ss = 0.0;
    for (int i = 0; i < 256; ++i) {
        const float v = Y[(size_t)(r0 + i) * NF + col];
        s  += (double)v;
        ss += (double)v * (double)v;
    }
    atomicAdd(&dsum[col], s);
    atomicAdd(&dsqs[col], ss);
}

// ---------------------------------------------------------------------------
// Kernel 4: finalize mean / rstd / boost (f64 + f32 copies)
// ---------------------------------------------------------------------------
__global__ __launch_bounds__(256) void stats_final(
    const double* __restrict__ dsum, const double* __restrict__ dsqs,
    const float* __restrict__ duty, const int* __restrict__ kp,
    double* __restrict__ mean64, double* __restrict__ rstd64, double* __restrict__ boost64,
    float* __restrict__ mean32, float* __restrict__ rstd32, float* __restrict__ boost32)
{
    const int c = blockIdx.x * 256 + threadIdx.x;
    const double m   = dsum[c] / (double)BATCH;
    const double var = dsqs[c] / (double)BATCH - m * m;
    const double rs  = 1.0 / sqrt(var + (double)BN_EPS);
    const double td  = (double)(*kp) / (double)NF;
    const double bf  = exp(td - (double)duty[c]);
    mean64[c] = m;  rstd64[c] = rs;  boost64[c] = bf;
    mean32[c] = (float)m; rstd32[c] = (float)rs; boost32[c] = (float)bf;
}

// ---------------------------------------------------------------------------
// Kernel 5: per-row BN-apply + boosted top-k (radix select, f32) with f64
// band refinement near the cutoff + scatter (in place). One block per row.
// ---------------------------------------------------------------------------
#define BAND 1e-4f
#define MAXCAND 64

__global__ __launch_bounds__(256) void topk_kernel(
    const float* __restrict__ mean32, const float* __restrict__ rstd32,
    const float* __restrict__ boost32,
    const double* __restrict__ mean64, const double* __restrict__ rstd64,
    const double* __restrict__ boost64,
    const int* __restrict__ kp,
    const float* __restrict__ X, const float* __restrict__ W,
    const int* __restrict__ Mk, const float* __restrict__ bias,
    float* __restrict__ Y)
{
    __shared__ float    yv[NF];
    __shared__ unsigned keys[NF];
    __shared__ unsigned hist[256];
    __shared__ unsigned scan[256];
    __shared__ unsigned s_bin, s_below;
    __shared__ double   red[256];
    __shared__ int      s_ncand, s_H;
    __shared__ int      cand_idx[MAXCAND];
    __shared__ double   cand_val[MAXCAND];
    __shared__ unsigned char cand_pick[MAXCAND];

    const int r = blockIdx.x;
    const int t = threadIdx.x;
    const int K = *kp;

    // load row, apply BN, compute orderable keys of boosted values
    for (int j = 0; j < 16; ++j) {
        const int n = j * 256 + t;
        const float v   = Y[(size_t)r * NF + n];
        const float ybn = (v - mean32[n]) * rstd32[n];
        yv[n] = ybn;
        const float bst = ybn * boost32[n];
        unsigned u = __float_as_uint(bst);
        u ^= (u & 0x80000000u) ? 0xFFFFFFFFu : 0x80000000u;  // monotonic map
        keys[n] = u;
    }
    __syncthreads();

    // 4-pass radix select: find T = K-th largest key
    unsigned curval = 0u, curmask = 0u;
    int remaining = K;
    for (int pass = 3; pass >= 0; --pass) {
        const int sh = pass * 8;
        hist[t] = 0u;
        __syncthreads();
        for (int j = 0; j < 16; ++j) {
            const unsigned u = keys[j * 256 + t];
            if ((u & curmask) == curval)
                atomicAdd(&hist[(u >> sh) & 255u], 1u);
        }
        __syncthreads();
        scan[t] = hist[t];
        __syncthreads();
        for (int off = 1; off < 256; off <<= 1) {
            const unsigned add = (t + off < 256) ? scan[t + off] : 0u;
            __syncthreads();
            scan[t] += add;
            __syncthreads();
        }
        if (scan[t] >= (unsigned)remaining &&
            (t == 255 || scan[t + 1] < (unsigned)remaining)) {
            s_bin = (unsigned)t;
            s_below = (t == 255) ? 0u : scan[t + 1];
        }
        __syncthreads();
        curval |= (s_bin << sh);
        curmask |= (255u << sh);
        remaining -= (int)s_below;
        __syncthreads();
    }

    const unsigned T = curval;

    // cutoff value as float (invert the monotonic map)
    const unsigned vT = (T & 0x80000000u) ? (T ^ 0x80000000u) : ~T;
    const float cut32 = __uint_as_float(vT);
    const float cutHi = cut32 + BAND;
    const float cutLo = cut32 - BAND;

    // classify: count definite-selects (H) and collect band candidates
    if (t == 0) { s_ncand = 0; s_H = 0; }
    __syncthreads();
    int locH = 0;
    for (int j = 0; j < 16; ++j) {
        const int n = j * 256 + t;
        const float b = yv[n] * boost32[n];
        if (b > cutHi) {
            locH++;
        } else if (b >= cutLo) {
            const int slot = atomicAdd(&s_ncand, 1);
            if (slot < MAXCAND) cand_idx[slot] = n;
        }
    }
    atomicAdd(&s_H, locH);
    __syncthreads();
    const int H = s_H;
    const bool overflow = (s_ncand > MAXCAND);
    const int ncand = overflow ? MAXCAND : s_ncand;
    int need = K - H;
    if (need < 0) need = 0;

    if (!overflow) {
        // recompute each candidate's boosted value in f64
        for (int c = 0; c < ncand; ++c) {
            const int n = cand_idx[c];
            const float* xr = X + (size_t)r * INF;
            const float* wn = W + (size_t)n * INF;
            const int*   mn = Mk + (size_t)n * INF;
            double s = 0.0;
            for (int i = t; i < INF; i += 256)
                s += (double)xr[i] * (double)(wn[i] * (float)mn[i]);
            red[t] = s;
            __syncthreads();
            for (int off = 128; off > 0; off >>= 1) {
                if (t < off) red[t] += red[t + off];
                __syncthreads();
            }
            if (t == 0) {
                const double y64 = red[0] + (double)bias[n];
                cand_val[c] = (y64 - mean64[n]) * rstd64[n] * boost64[n];
                cand_pick[c] = 0;
            }
            __syncthreads();
        }
        // serial exact selection of `need` best (value desc, index asc)
        if (t == 0) {
            for (int p = 0; p < need; ++p) {
                int best = -1;
                for (int c = 0; c < ncand; ++c) {
                    if (cand_pick[c]) continue;
                    if (best < 0 || cand_val[c] > cand_val[best] ||
                        (cand_val[c] == cand_val[best] && cand_idx[c] < cand_idx[best]))
                        best = c;
                }
                if (best < 0) break;
                cand_pick[best] = 1;
            }
        }
        __syncthreads();
        // build selection flags in keys[]
        for (int j = 0; j < 16; ++j) {
            const int n = j * 256 + t;
            const float b = yv[n] * boost32[n];
            keys[n] = (b > cutHi) ? 1u : 0u;
        }
        __syncthreads();
        if (t < ncand && cand_pick[t]) keys[cand_idx[t]] = 1u;
        __syncthreads();
    } else {
        // fallback: pure f32 stable selection (lowest-index ties at T)
        const int fneed = remaining;
        unsigned cnt = 0u;
        for (int j = 0; j < 16; ++j) cnt += (keys[t * 16 + j] == T) ? 1u : 0u;
        scan[t] = cnt;
        __syncthreads();
        for (int off = 1; off < 256; off <<= 1) {
            const unsigned add = (t >= off) ? scan[t - off] : 0u;
            __syncthreads();
            scan[t] += add;
            __syncthreads();
        }
        unsigned rank = scan[t] - cnt;
        for (int j = 0; j < 16; ++j) {
            const int n = t * 16 + j;
            const unsigned u = keys[n];
            bool sel;
            if (u == T) { sel = ((int)rank < fneed); rank++; }
            else        { sel = (u > T); }
            keys[n] = sel ? 1u : 0u;
        }
        __syncthreads();
    }

    // coalesced in-place write
    for (int j = 0; j < 16; ++j) {
        const int n = j * 256 + t;
        Y[(size_t)r * NF + n] = keys[n] ? yv[n] : 0.0f;
    }
}

// ---------------------------------------------------------------------------
extern "C" void kernel_launch(void* const* d_in, const int* in_sizes, int n_in,
                              void* d_out, int out_size, void* d_ws, size_t ws_size,
                              hipStream_t stream)
{
    const float* x     = (const float*)d_in[0];
    const float* W     = (const float*)d_in[1];
    const float* b     = (const float*)d_in[2];
    const int*   wmask = (const int*)d_in[3];
    const float* duty  = (const float*)d_in[4];
    const int*   kp    = (const int*)d_in[5];
    float* out = (float*)d_out;

    double* dsum   = (double*)d_ws;          // [4096]
    double* dsqs   = dsum + NF;              // [4096]
    double* mean64 = dsqs + NF;              // [4096]
    double* rstd64 = mean64 + NF;            // [4096]
    double* boost64 = rstd64 + NF;           // [4096]
    float*  mean32 = (float*)(boost64 + NF); // [4096]
    float*  rstd32 = mean32 + NF;            // [4096]
    float*  boost32 = rstd32 + NF;           // [4096]

    hipLaunchKernelGGL(zero_ws, dim3(2 * NF / 256), dim3(256), 0, stream, dsum);
    hipLaunchKernelGGL(gemm_mask_f32k, dim3(NF / 128, BATCH / 128), dim3(256), 0, stream,
                       x, W, wmask, b, out);
    hipLaunchKernelGGL(stats_partial, dim3(NF / 256, BATCH / 256), dim3(256), 0, stream,
                       out, dsum, dsqs);
    hipLaunchKernelGGL(stats_final, dim3(NF / 256), dim3(256), 0, stream,
                       dsum, dsqs, duty, kp,
                       mean64, rstd64, boost64, mean32, rstd32, boost32);
    hipLaunchKernelGGL(topk_kernel, dim3(BATCH), dim3(256), 0, stream,
                       mean32, rstd32, boost32, mean64, rstd64, boost64, kp,
                       x, W, wmask, b, out);
}

// Round 4
// 1189.821 us; speedup vs baseline: 2.1904x; 2.1904x over previous
//
#include <hip/hip_runtime.h>

// Problem constants (fixed-shape: B=8192, IN=1024, N=4096, K=409)
#define BATCH 8192
#define INF   1024
#define NF    4096
#define BN_EPS 1e-5

// ---------------------------------------------------------------------------
// Kernel 1: zero the f64 stats accumulators (2*4096 doubles)
// ---------------------------------------------------------------------------
__global__ void zero_ws(double* __restrict__ p) {
    p[blockIdx.x * 256 + threadIdx.x] = 0.0;
}

// ---------------------------------------------------------------------------
// Kernel 2: masked f32 GEMM, f32 inner FMA, chunked (Kc=32) f64 shadow.
// Tile 128x64 (MxN), BK=16, 256 threads, 8x4 acc/thread.
// State: 32 f32 acc + 32 f64 shadow = 96 VGPR -> no spill (R3 lesson).
// ---------------------------------------------------------------------------
__global__ __launch_bounds__(256) void gemm_mask_f32s(
    const float* __restrict__ X, const float* __restrict__ W,
    const int* __restrict__ Mk, const float* __restrict__ bias,
    float* __restrict__ Y)
{
    __shared__ float As[16][132];   // [k][row], 128 rows + pad
    __shared__ float Bs[16][68];    // [k][col], 64 cols + pad

    const int t = threadIdx.x;
    const int row0 = blockIdx.y * 128;
    const int col0 = blockIdx.x * 64;

    // A loads: 128 rows x 16 k = 2 float4 per thread
    const int alr = t >> 1;            // 0..127
    const int alk = (t & 1) * 8;       // 0 or 8
    // B loads: 64 rows x 16 k -> 1 float4 + 1 int4 per thread
    const int blr = t >> 2;            // 0..63
    const int blk = (t & 3) * 4;       // 0,4,8,12

    const float* Xp = X + (size_t)(row0 + alr) * INF + alk;
    const float* Wp = W + (size_t)(col0 + blr) * INF + blk;
    const int*   Mp = Mk + (size_t)(col0 + blr) * INF + blk;

    const int tx = t & 15;             // col group: tx*4
    const int ty = t >> 4;             // row group: ty*8

    float  acc[8][4];
    double sh[8][4];
#pragma unroll
    for (int i = 0; i < 8; ++i)
#pragma unroll
        for (int j = 0; j < 4; ++j) { acc[i][j] = 0.0f; sh[i][j] = 0.0; }

    for (int k0 = 0; k0 < INF; k0 += 16) {
        const float4 a0 = *(const float4*)(Xp + k0);
        const float4 a1 = *(const float4*)(Xp + k0 + 4);
        float4 b0 = *(const float4*)(Wp + k0);
        const int4 m0 = *(const int4*)(Mp + k0);
        b0.x *= (float)m0.x; b0.y *= (float)m0.y;
        b0.z *= (float)m0.z; b0.w *= (float)m0.w;

        __syncthreads();   // protect previous iteration's LDS reads
        As[alk + 0][alr] = a0.x; As[alk + 1][alr] = a0.y;
        As[alk + 2][alr] = a0.z; As[alk + 3][alr] = a0.w;
        As[alk + 4][alr] = a1.x; As[alk + 5][alr] = a1.y;
        As[alk + 6][alr] = a1.z; As[alk + 7][alr] = a1.w;
        Bs[blk + 0][blr] = b0.x; Bs[blk + 1][blr] = b0.y;
        Bs[blk + 2][blr] = b0.z; Bs[blk + 3][blr] = b0.w;
        __syncthreads();

#pragma unroll
        for (int kk = 0; kk < 16; ++kk) {
            const float4 av0 = *(const float4*)&As[kk][ty * 8];
            const float4 av1 = *(const float4*)&As[kk][ty * 8 + 4];
            const float4 bv  = *(const float4*)&Bs[kk][tx * 4];
            const float a[8] = {av0.x, av0.y, av0.z, av0.w, av1.x, av1.y, av1.z, av1.w};
            const float b[4] = {bv.x, bv.y, bv.z, bv.w};
#pragma unroll
            for (int i = 0; i < 8; ++i)
#pragma unroll
                for (int j = 0; j < 4; ++j)
                    acc[i][j] = fmaf(a[i], b[j], acc[i][j]);
        }

        if (k0 & 16) {   // drain f32 chunk (Kc=32) into f64 shadow
#pragma unroll
            for (int i = 0; i < 8; ++i)
#pragma unroll
                for (int j = 0; j < 4; ++j) { sh[i][j] += (double)acc[i][j]; acc[i][j] = 0.0f; }
        }
    }

    // epilogue: add bias in f64, store f32
#pragma unroll
    for (int i = 0; i < 8; ++i) {
        const int rr = row0 + ty * 8 + i;
        float4 o;
        o.x = (float)(sh[i][0] + (double)bias[col0 + tx * 4 + 0]);
        o.y = (float)(sh[i][1] + (double)bias[col0 + tx * 4 + 1]);
        o.z = (float)(sh[i][2] + (double)bias[col0 + tx * 4 + 2]);
        o.w = (float)(sh[i][3] + (double)bias[col0 + tx * 4 + 3]);
        *(float4*)&Y[(size_t)rr * NF + col0 + tx * 4] = o;
    }
}

// ---------------------------------------------------------------------------
// Kernel 3: per-column partial sums (f64) over 256-row chunks
// ---------------------------------------------------------------------------
__global__ __launch_bounds__(256) void stats_partial(
    const float* __restrict__ Y, double* __restrict__ dsum, double* __restrict__ dsqs)
{
    const int col = blockIdx.x * 256 + threadIdx.x;
    const int r0  = blockIdx.y * 256;
    double s = 0.0, ss = 0.0;
    for (int i = 0; i < 256; ++i) {
        const float v = Y[(size_t)(r0 + i) * NF + col];
        s  += (double)v;
        ss += (double)v * (double)v;
    }
    atomicAdd(&dsum[col], s);
    atomicAdd(&dsqs[col], ss);
}

// ---------------------------------------------------------------------------
// Kernel 4: finalize mean / rstd / boost (f64 + f32 copies)
// ---------------------------------------------------------------------------
__global__ __launch_bounds__(256) void stats_final(
    const double* __restrict__ dsum, const double* __restrict__ dsqs,
    const float* __restrict__ duty, const int* __restrict__ kp,
    double* __restrict__ mean64, double* __restrict__ rstd64, double* __restrict__ boost64,
    float* __restrict__ mean32, float* __restrict__ rstd32, float* __restrict__ boost32)
{
    const int c = blockIdx.x * 256 + threadIdx.x;
    const double m   = dsum[c] / (double)BATCH;
    const double var = dsqs[c] / (double)BATCH - m * m;
    const double rs  = 1.0 / sqrt(var + (double)BN_EPS);
    const double td  = (double)(*kp) / (double)NF;
    const double bf  = exp(td - (double)duty[c]);
    mean64[c] = m;  rstd64[c] = rs;  boost64[c] = bf;
    mean32[c] = (float)m; rstd32[c] = (float)rs; boost32[c] = (float)bf;
}

// ---------------------------------------------------------------------------
// Kernel 5: per-row BN-apply + boosted top-k (radix select, f32) with f64
// band refinement near the cutoff + scatter (in place). One block per row.
// ---------------------------------------------------------------------------
#define BAND 1e-4f
#define MAXCAND 64

__global__ __launch_bounds__(256) void topk_kernel(
    const float* __restrict__ mean32, const float* __restrict__ rstd32,
    const float* __restrict__ boost32,
    const double* __restrict__ mean64, const double* __restrict__ rstd64,
    const double* __restrict__ boost64,
    const int* __restrict__ kp,
    const float* __restrict__ X, const float* __restrict__ W,
    const int* __restrict__ Mk, const float* __restrict__ bias,
    float* __restrict__ Y)
{
    __shared__ float    yv[NF];
    __shared__ unsigned keys[NF];
    __shared__ unsigned hist[256];
    __shared__ unsigned scan[256];
    __shared__ unsigned s_bin, s_below;
    __shared__ double   red[256];
    __shared__ int      s_ncand, s_H;
    __shared__ int      cand_idx[MAXCAND];
    __shared__ double   cand_val[MAXCAND];
    __shared__ unsigned char cand_pick[MAXCAND];

    const int r = blockIdx.x;
    const int t = threadIdx.x;
    const int K = *kp;

    // load row, apply BN, compute orderable keys of boosted values
    for (int j = 0; j < 16; ++j) {
        const int n = j * 256 + t;
        const float v   = Y[(size_t)r * NF + n];
        const float ybn = (v - mean32[n]) * rstd32[n];
        yv[n] = ybn;
        const float bst = ybn * boost32[n];
        unsigned u = __float_as_uint(bst);
        u ^= (u & 0x80000000u) ? 0xFFFFFFFFu : 0x80000000u;  // monotonic map
        keys[n] = u;
    }
    __syncthreads();

    // 4-pass radix select: find T = K-th largest key
    unsigned curval = 0u, curmask = 0u;
    int remaining = K;
    for (int pass = 3; pass >= 0; --pass) {
        const int sh = pass * 8;
        hist[t] = 0u;
        __syncthreads();
        for (int j = 0; j < 16; ++j) {
            const unsigned u = keys[j * 256 + t];
            if ((u & curmask) == curval)
                atomicAdd(&hist[(u >> sh) & 255u], 1u);
        }
        __syncthreads();
        scan[t] = hist[t];
        __syncthreads();
        for (int off = 1; off < 256; off <<= 1) {
            const unsigned add = (t + off < 256) ? scan[t + off] : 0u;
            __syncthreads();
            scan[t] += add;
            __syncthreads();
        }
        if (scan[t] >= (unsigned)remaining &&
            (t == 255 || scan[t + 1] < (unsigned)remaining)) {
            s_bin = (unsigned)t;
            s_below = (t == 255) ? 0u : scan[t + 1];
        }
        __syncthreads();
        curval |= (s_bin << sh);
        curmask |= (255u << sh);
        remaining -= (int)s_below;
        __syncthreads();
    }

    const unsigned T = curval;

    // cutoff value as float (invert the monotonic map)
    const unsigned vT = (T & 0x80000000u) ? (T ^ 0x80000000u) : ~T;
    const float cut32 = __uint_as_float(vT);
    const float cutHi = cut32 + BAND;
    const float cutLo = cut32 - BAND;

    // classify: count definite-selects (H) and collect band candidates
    if (t == 0) { s_ncand = 0; s_H = 0; }
    __syncthreads();
    int locH = 0;
    for (int j = 0; j < 16; ++j) {
        const int n = j * 256 + t;
        const float b = yv[n] * boost32[n];
        if (b > cutHi) {
            locH++;
        } else if (b >= cutLo) {
            const int slot = atomicAdd(&s_ncand, 1);
            if (slot < MAXCAND) cand_idx[slot] = n;
        }
    }
    atomicAdd(&s_H, locH);
    __syncthreads();
    const int H = s_H;
    const bool overflow = (s_ncand > MAXCAND);
    const int ncand = overflow ? MAXCAND : s_ncand;
    int need = K - H;
    if (need < 0) need = 0;

    if (!overflow) {
        // recompute each candidate's boosted value in f64
        for (int c = 0; c < ncand; ++c) {
            const int n = cand_idx[c];
            const float* xr = X + (size_t)r * INF;
            const float* wn = W + (size_t)n * INF;
            const int*   mn = Mk + (size_t)n * INF;
            double s = 0.0;
            for (int i = t; i < INF; i += 256)
                s += (double)xr[i] * (double)(wn[i] * (float)mn[i]);
            red[t] = s;
            __syncthreads();
            for (int off = 128; off > 0; off >>= 1) {
                if (t < off) red[t] += red[t + off];
                __syncthreads();
            }
            if (t == 0) {
                const double y64 = red[0] + (double)bias[n];
                cand_val[c] = (y64 - mean64[n]) * rstd64[n] * boost64[n];
                cand_pick[c] = 0;
            }
            __syncthreads();
        }
        // serial exact selection of `need` best (value desc, index asc)
        if (t == 0) {
            for (int p = 0; p < need; ++p) {
                int best = -1;
                for (int c = 0; c < ncand; ++c) {
                    if (cand_pick[c]) continue;
                    if (best < 0 || cand_val[c] > cand_val[best] ||
                        (cand_val[c] == cand_val[best] && cand_idx[c] < cand_idx[best]))
                        best = c;
                }
                if (best < 0) break;
                cand_pick[best] = 1;
            }
        }
        __syncthreads();
        // build selection flags in keys[]
        for (int j = 0; j < 16; ++j) {
            const int n = j * 256 + t;
            const float b = yv[n] * boost32[n];
            keys[n] = (b > cutHi) ? 1u : 0u;
        }
        __syncthreads();
        if (t < ncand && cand_pick[t]) keys[cand_idx[t]] = 1u;
        __syncthreads();
    } else {
        // fallback: pure f32 stable selection (lowest-index ties at T)
        const int fneed = remaining;
        unsigned cnt = 0u;
        for (int j = 0; j < 16; ++j) cnt += (keys[t * 16 + j] == T) ? 1u : 0u;
        scan[t] = cnt;
        __syncthreads();
        for (int off = 1; off < 256; off <<= 1) {
            const unsigned add = (t >= off) ? scan[t - off] : 0u;
            __syncthreads();
            scan[t] += add;
            __syncthreads();
        }
        unsigned rank = scan[t] - cnt;
        for (int j = 0; j < 16; ++j) {
            const int n = t * 16 + j;
            const unsigned u = keys[n];
            bool sel;
            if (u == T) { sel = ((int)rank < fneed); rank++; }
            else        { sel = (u > T); }
            keys[n] = sel ? 1u : 0u;
        }
        __syncthreads();
    }

    // coalesced in-place write
    for (int j = 0; j < 16; ++j) {
        const int n = j * 256 + t;
        Y[(size_t)r * NF + n] = keys[n] ? yv[n] : 0.0f;
    }
}

// ---------------------------------------------------------------------------
extern "C" void kernel_launch(void* const* d_in, const int* in_sizes, int n_in,
                              void* d_out, int out_size, void* d_ws, size_t ws_size,
                              hipStream_t stream)
{
    const float* x     = (const float*)d_in[0];
    const float* W     = (const float*)d_in[1];
    const float* b     = (const float*)d_in[2];
    const int*   wmask = (const int*)d_in[3];
    const float* duty  = (const float*)d_in[4];
    const int*   kp    = (const int*)d_in[5];
    float* out = (float*)d_out;

    double* dsum   = (double*)d_ws;          // [4096]
    double* dsqs   = dsum + NF;              // [4096]
    double* mean64 = dsqs + NF;              // [4096]
    double* rstd64 = mean64 + NF;            // [4096]
    double* boost64 = rstd64 + NF;           // [4096]
    float*  mean32 = (float*)(boost64 + NF); // [4096]
    float*  rstd32 = mean32 + NF;            // [4096]
    float*  boost32 = rstd32 + NF;           // [4096]

    hipLaunchKernelGGL(zero_ws, dim3(2 * NF / 256), dim3(256), 0, stream, dsum);
    hipLaunchKernelGGL(gemm_mask_f32s, dim3(NF / 64, BATCH / 128), dim3(256), 0, stream,
                       x, W, wmask, b, out);
    hipLaunchKernelGGL(stats_partial, dim3(NF / 256, BATCH / 256), dim3(256), 0, stream,
                       out, dsum, dsqs);
    hipLaunchKernelGGL(stats_final, dim3(NF / 256), dim3(256), 0, stream,
                       dsum, dsqs, duty, kp,
                       mean64, rstd64, boost64, mean32, rstd32, boost32);
    hipLaunchKernelGGL(topk_kernel, dim3(BATCH), dim3(256), 0, stream,
                       mean32, rstd32, boost32, mean64, rstd64, boost64, kp,
                       x, W, wmask, b, out);
}

// Round 6
// 755.902 us; speedup vs baseline: 3.4478x; 1.5740x over previous
//
#include <hip/hip_runtime.h>
#include <string.h>

// Problem constants (fixed-shape: B=8192, IN=1024, N=4096, K=409)
#define BATCH 8192
#define INF   1024
#define NF    4096
#define BN_EPS 1e-5

typedef __attribute__((ext_vector_type(8))) short short8v;
typedef __attribute__((ext_vector_type(4))) float f32x4;

// ---------------------------------------------------------------------------
// Kernel 1: zero the f64 stats accumulators (2*4096 doubles)
// ---------------------------------------------------------------------------
__global__ void zero_ws(double* __restrict__ p) {
    p[blockIdx.x * 256 + threadIdx.x] = 0.0;
}

// ---------------------------------------------------------------------------
// Exact 3-way bf16 truncation split: x == bf16(h0)+bf16(h1)+bf16(h2) EXACTLY
// (f32 has 24 significand bits; h0/h1/h2 take bits 1-8 / 9-16 / 17-24).
// ---------------------------------------------------------------------------
__device__ __forceinline__ void split3(float x, ushort& h0, ushort& h1, ushort& h2) {
    const unsigned u0 = __float_as_uint(x) & 0xFFFF0000u;
    const float    r1 = x - __uint_as_float(u0);
    const unsigned u1 = __float_as_uint(r1) & 0xFFFF0000u;
    const float    r2 = r1 - __uint_as_float(u1);   // <=8 significant bits: bf16-exact
    h0 = (ushort)(u0 >> 16);
    h1 = (ushort)(u1 >> 16);
    h2 = (ushort)(__float_as_uint(r2) >> 16);
}

// ---------------------------------------------------------------------------
// Kernel 2: masked GEMM via bf16 MFMA, exact split, 9 cross-products.
// Y[r][n] = sum_i x[r][i]*W[n][i]*mask[n][i] + b[n]
// Tile 128(M)x128(N), BK=32, 512 threads = 8 waves (4M x 2N), wave = 32x64
// = 2x4 frags of mfma_f32_16x16x32_bf16. f32 frag accs drained into f64
// shadow every Kc=64 -> total per-element error ~4e-8 (< R4's passing 7e-8).
// ---------------------------------------------------------------------------
__global__ __launch_bounds__(512) void gemm_mfma_split(
    const float* __restrict__ X, const float* __restrict__ W,
    const int* __restrict__ Mk, const float* __restrict__ bias,
    float* __restrict__ Y)
{
    // LDS: 6 tiles [128 rows][40 shorts] (32 data + 8 pad -> 80B rows,
    // frag reads and staged writes conflict-free). 6*10240B = 60KB.
    __shared__ __align__(16) ushort a0s[128 * 40];
    __shared__ __align__(16) ushort a1s[128 * 40];
    __shared__ __align__(16) ushort a2s[128 * 40];
    __shared__ __align__(16) ushort b0s[128 * 40];
    __shared__ __align__(16) ushort b1s[128 * 40];
    __shared__ __align__(16) ushort b2s[128 * 40];

    const int t = threadIdx.x;
    const int row0 = blockIdx.y * 128;
    const int col0 = blockIdx.x * 128;

    // staging assignment: thread -> (row, k-block of 8)
    const int srow = t >> 2;          // 0..127
    const int skb  = (t & 3) * 8;     // 0,8,16,24

    const float* Xp = X + (size_t)(row0 + srow) * INF + skb;
    const float* Wp = W + (size_t)(col0 + srow) * INF + skb;
    const int*   Mp = Mk + (size_t)(col0 + srow) * INF + skb;

    // wave/lane geometry
    const int l   = t & 63;
    const int l15 = l & 15;
    const int hi  = l >> 4;           // 0..3
    const int wid = t >> 6;           // 0..7
    const int wm  = wid >> 1;         // 0..3 : m-offset wm*32
    const int wn  = wid & 1;          // 0..1 : n-offset wn*64

    f32x4  acc[2][4];
    double sh[2][4][4];
#pragma unroll
    for (int mf = 0; mf < 2; ++mf)
#pragma unroll
        for (int nf = 0; nf < 4; ++nf) {
            acc[mf][nf] = (f32x4){0.f, 0.f, 0.f, 0.f};
#pragma unroll
            for (int r = 0; r < 4; ++r) sh[mf][nf][r] = 0.0;
        }

    // prefetch tile 0 into registers
    float4 xA0 = *(const float4*)(Xp);
    float4 xA1 = *(const float4*)(Xp + 4);
    float4 wB0 = *(const float4*)(Wp);
    float4 wB1 = *(const float4*)(Wp + 4);
    int4   mB0 = *(const int4*)(Mp);
    int4   mB1 = *(const int4*)(Mp + 4);

    for (int k0 = 0; k0 < INF; k0 += 32) {
        __syncthreads();   // previous iteration's frag reads done

        // ---- split + stage A ----
        {
            const float v[8] = {xA0.x, xA0.y, xA0.z, xA0.w, xA1.x, xA1.y, xA1.z, xA1.w};
            short8v s0, s1, s2;
#pragma unroll
            for (int i = 0; i < 8; ++i) {
                ushort h0, h1, h2;
                split3(v[i], h0, h1, h2);
                s0[i] = (short)h0; s1[i] = (short)h1; s2[i] = (short)h2;
            }
            const int off = srow * 40 + skb;
            *(short8v*)&a0s[off] = s0;
            *(short8v*)&a1s[off] = s1;
            *(short8v*)&a2s[off] = s2;
        }
        // ---- mask + split + stage B ----
        {
            const float wv[8] = {wB0.x * (float)mB0.x, wB0.y * (float)mB0.y,
                                 wB0.z * (float)mB0.z, wB0.w * (float)mB0.w,
                                 wB1.x * (float)mB1.x, wB1.y * (float)mB1.y,
                                 wB1.z * (float)mB1.z, wB1.w * (float)mB1.w};
            short8v s0, s1, s2;
#pragma unroll
            for (int i = 0; i < 8; ++i) {
                ushort h0, h1, h2;
                split3(wv[i], h0, h1, h2);
                s0[i] = (short)h0; s1[i] = (short)h1; s2[i] = (short)h2;
            }
            const int off = srow * 40 + skb;
            *(short8v*)&b0s[off] = s0;
            *(short8v*)&b1s[off] = s1;
            *(short8v*)&b2s[off] = s2;
        }
        __syncthreads();

        // ---- prefetch next tile (overlaps frag reads + MFMAs) ----
        if (k0 + 32 < INF) {
            const int kn = k0 + 32;
            xA0 = *(const float4*)(Xp + kn);
            xA1 = *(const float4*)(Xp + kn + 4);
            wB0 = *(const float4*)(Wp + kn);
            wB1 = *(const float4*)(Wp + kn + 4);
            mB0 = *(const int4*)(Mp + kn);
            mB1 = *(const int4*)(Mp + kn + 4);
        }

        // ---- load fragments ----
        short8v A[2][3], B[4][3];
#pragma unroll
        for (int mf = 0; mf < 2; ++mf) {
            const int roff = (wm * 32 + mf * 16 + l15) * 40 + hi * 8;
            A[mf][0] = *(const short8v*)&a0s[roff];
            A[mf][1] = *(const short8v*)&a1s[roff];
            A[mf][2] = *(const short8v*)&a2s[roff];
        }
#pragma unroll
        for (int nf = 0; nf < 4; ++nf) {
            const int roff = (wn * 64 + nf * 16 + l15) * 40 + hi * 8;
            B[nf][0] = *(const short8v*)&b0s[roff];
            B[nf][1] = *(const short8v*)&b1s[roff];
            B[nf][2] = *(const short8v*)&b2s[roff];
        }

        // ---- 9 cross-products per frag (exact split => exact products) ----
#pragma unroll
        for (int mf = 0; mf < 2; ++mf)
#pragma unroll
            for (int nf = 0; nf < 4; ++nf) {
                f32x4 c = acc[mf][nf];
                c = __builtin_amdgcn_mfma_f32_16x16x32_bf16(A[mf][0], B[nf][0], c, 0, 0, 0);
                c = __builtin_amdgcn_mfma_f32_16x16x32_bf16(A[mf][0], B[nf][1], c, 0, 0, 0);
                c = __builtin_amdgcn_mfma_f32_16x16x32_bf16(A[mf][1], B[nf][0], c, 0, 0, 0);
                c = __builtin_amdgcn_mfma_f32_16x16x32_bf16(A[mf][1], B[nf][1], c, 0, 0, 0);
                c = __builtin_amdgcn_mfma_f32_16x16x32_bf16(A[mf][0], B[nf][2], c, 0, 0, 0);
                c = __builtin_amdgcn_mfma_f32_16x16x32_bf16(A[mf][2], B[nf][0], c, 0, 0, 0);
                c = __builtin_amdgcn_mfma_f32_16x16x32_bf16(A[mf][1], B[nf][2], c, 0, 0, 0);
                c = __builtin_amdgcn_mfma_f32_16x16x32_bf16(A[mf][2], B[nf][1], c, 0, 0, 0);
                c = __builtin_amdgcn_mfma_f32_16x16x32_bf16(A[mf][2], B[nf][2], c, 0, 0, 0);
                acc[mf][nf] = c;
            }

        if (k0 & 32) {   // drain f32 frag accs into f64 shadow every Kc=64
#pragma unroll
            for (int mf = 0; mf < 2; ++mf)
#pragma unroll
                for (int nf = 0; nf < 4; ++nf) {
#pragma unroll
                    for (int r = 0; r < 4; ++r) sh[mf][nf][r] += (double)acc[mf][nf][r];
                    acc[mf][nf] = (f32x4){0.f, 0.f, 0.f, 0.f};
                }
        }
    }

    // ---- epilogue: add bias in f64, store f32 ----
#pragma unroll
    for (int mf = 0; mf < 2; ++mf)
#pragma unroll
        for (int nf = 0; nf < 4; ++nf) {
            const int col = col0 + wn * 64 + nf * 16 + l15;
            const double bb = (double)bias[col];
#pragma unroll
            for (int r = 0; r < 4; ++r) {
                const int row = row0 + wm * 32 + mf * 16 + hi * 4 + r;
                Y[(size_t)row * NF + col] = (float)(sh[mf][nf][r] + bb);
            }
        }
}

// ---------------------------------------------------------------------------
// Kernel 3: per-column partial sums (f64) over 256-row chunks
// ---------------------------------------------------------------------------
__global__ __launch_bounds__(256) void stats_partial(
    const float* __restrict__ Y, double* __restrict__ dsum, double* __restrict__ dsqs)
{
    const int col = blockIdx.x * 256 + threadIdx.x;
    const int r0  = blockIdx.y * 256;
    double s = 0.0, ss = 0.0;
    for (int i = 0; i < 256; ++i) {
        const float v = Y[(size_t)(r0 + i) * NF + col];
        s  += (double)v;
        ss += (double)v * (double)v;
    }
    atomicAdd(&dsum[col], s);
    atomicAdd(&dsqs[col], ss);
}

// ---------------------------------------------------------------------------
// Kernel 4: finalize mean / rstd / boost (f64 + f32 copies)
// ---------------------------------------------------------------------------
__global__ __launch_bounds__(256) void stats_final(
    const double* __restrict__ dsum, const double* __restrict__ dsqs,
    const float* __restrict__ duty, const int* __restrict__ kp,
    double* __restrict__ mean64, double* __restrict__ rstd64, double* __restrict__ boost64,
    float* __restrict__ mean32, float* __restrict__ rstd32, float* __restrict__ boost32)
{
    const int c = blockIdx.x * 256 + threadIdx.x;
    const double m   = dsum[c] / (double)BATCH;
    const double var = dsqs[c] / (double)BATCH - m * m;
    const double rs  = 1.0 / sqrt(var + (double)BN_EPS);
    const double td  = (double)(*kp) / (double)NF;
    const double bf  = exp(td - (double)duty[c]);
    mean64[c] = m;  rstd64[c] = rs;  boost64[c] = bf;
    mean32[c] = (float)m; rstd32[c] = (float)rs; boost32[c] = (float)bf;
}

// ---------------------------------------------------------------------------
// Kernel 5: per-row BN-apply + boosted top-k (radix select, f32) with f64
// band refinement near the cutoff + scatter (in place). One block per row.
// ---------------------------------------------------------------------------
#define BAND 1e-4f
#define MAXCAND 64

__global__ __launch_bounds__(256) void topk_kernel(
    const float* __restrict__ mean32, const float* __restrict__ rstd32,
    const float* __restrict__ boost32,
    const double* __restrict__ mean64, const double* __restrict__ rstd64,
    const double* __restrict__ boost64,
    const int* __restrict__ kp,
    const float* __restrict__ X, const float* __restrict__ W,
    const int* __restrict__ Mk, const float* __restrict__ bias,
    float* __restrict__ Y)
{
    __shared__ float    yv[NF];
    __shared__ unsigned keys[NF];
    __shared__ unsigned hist[256];
    __shared__ unsigned scan[256];
    __shared__ unsigned s_bin, s_below;
    __shared__ double   red[256];
    __shared__ int      s_ncand, s_H;
    __shared__ int      cand_idx[MAXCAND];
    __shared__ double   cand_val[MAXCAND];
    __shared__ unsigned char cand_pick[MAXCAND];

    const int r = blockIdx.x;
    const int t = threadIdx.x;
    const int K = *kp;

    // load row, apply BN, compute orderable keys of boosted values
    for (int j = 0; j < 16; ++j) {
        const int n = j * 256 + t;
        const float v   = Y[(size_t)r * NF + n];
        const float ybn = (v - mean32[n]) * rstd32[n];
        yv[n] = ybn;
        const float bst = ybn * boost32[n];
        unsigned u = __float_as_uint(bst);
        u ^= (u & 0x80000000u) ? 0xFFFFFFFFu : 0x80000000u;  // monotonic map
        keys[n] = u;
    }
    __syncthreads();

    // 4-pass radix select: find T = K-th largest key
    unsigned curval = 0u, curmask = 0u;
    int remaining = K;
    for (int pass = 3; pass >= 0; --pass) {
        const int sh = pass * 8;
        hist[t] = 0u;
        __syncthreads();
        for (int j = 0; j < 16; ++j) {
            const unsigned u = keys[j * 256 + t];
            if ((u & curmask) == curval)
                atomicAdd(&hist[(u >> sh) & 255u], 1u);
        }
        __syncthreads();
        scan[t] = hist[t];
        __syncthreads();
        for (int off = 1; off < 256; off <<= 1) {
            const unsigned add = (t + off < 256) ? scan[t + off] : 0u;
            __syncthreads();
            scan[t] += add;
            __syncthreads();
        }
        if (scan[t] >= (unsigned)remaining &&
            (t == 255 || scan[t + 1] < (unsigned)remaining)) {
            s_bin = (unsigned)t;
            s_below = (t == 255) ? 0u : scan[t + 1];
        }
        __syncthreads();
        curval |= (s_bin << sh);
        curmask |= (255u << sh);
        remaining -= (int)s_below;
        __syncthreads();
    }

    const unsigned T = curval;

    // cutoff value as float (invert the monotonic map)
    const unsigned vT = (T & 0x80000000u) ? (T ^ 0x80000000u) : ~T;
    const float cut32 = __uint_as_float(vT);
    const float cutHi = cut32 + BAND;
    const float cutLo = cut32 - BAND;

    // classify: count definite-selects (H) and collect band candidates
    if (t == 0) { s_ncand = 0; s_H = 0; }
    __syncthreads();
    int locH = 0;
    for (int j = 0; j < 16; ++j) {
        const int n = j * 256 + t;
        const float b = yv[n] * boost32[n];
        if (b > cutHi) {
            locH++;
        } else if (b >= cutLo) {
            const int slot = atomicAdd(&s_ncand, 1);
            if (slot < MAXCAND) cand_idx[slot] = n;
        }
    }
    atomicAdd(&s_H, locH);
    __syncthreads();
    const int H = s_H;
    const bool overflow = (s_ncand > MAXCAND);
    const int ncand = overflow ? MAXCAND : s_ncand;
    int need = K - H;
    if (need < 0) need = 0;

    if (!overflow) {
        // recompute each candidate's boosted value in f64
        for (int c = 0; c < ncand; ++c) {
            const int n = cand_idx[c];
            const float* xr = X + (size_t)r * INF;
            const float* wn = W + (size_t)n * INF;
            const int*   mn = Mk + (size_t)n * INF;
            double s = 0.0;
            for (int i = t; i < INF; i += 256)
                s += (double)xr[i] * (double)(wn[i] * (float)mn[i]);
            red[t] = s;
            __syncthreads();
            for (int off = 128; off > 0; off >>= 1) {
                if (t < off) red[t] += red[t + off];
                __syncthreads();
            }
            if (t == 0) {
                const double y64 = red[0] + (double)bias[n];
                cand_val[c] = (y64 - mean64[n]) * rstd64[n] * boost64[n];
                cand_pick[c] = 0;
            }
            __syncthreads();
        }
        // serial exact selection of `need` best (value desc, index asc)
        if (t == 0) {
            for (int p = 0; p < need; ++p) {
                int best = -1;
                for (int c = 0; c < ncand; ++c) {
                    if (cand_pick[c]) continue;
                    if (best < 0 || cand_val[c] > cand_val[best] ||
                        (cand_val[c] == cand_val[best] && cand_idx[c] < cand_idx[best]))
                        best = c;
                }
                if (best < 0) break;
                cand_pick[best] = 1;
            }
        }
        __syncthreads();
        // build selection flags in keys[]
        for (int j = 0; j < 16; ++j) {
            const int n = j * 256 + t;
            const float b = yv[n] * boost32[n];
            keys[n] = (b > cutHi) ? 1u : 0u;
        }
        __syncthreads();
        if (t < ncand && cand_pick[t]) keys[cand_idx[t]] = 1u;
        __syncthreads();
    } else {
        // fallback: pure f32 stable selection (lowest-index ties at T)
        const int fneed = remaining;
        unsigned cnt = 0u;
        for (int j = 0; j < 16; ++j) cnt += (keys[t * 16 + j] == T) ? 1u : 0u;
        scan[t] = cnt;
        __syncthreads();
        for (int off = 1; off < 256; off <<= 1) {
            const unsigned add = (t >= off) ? scan[t - off] : 0u;
            __syncthreads();
            scan[t] += add;
            __syncthreads();
        }
        unsigned rank = scan[t] - cnt;
        for (int j = 0; j < 16; ++j) {
            const int n = t * 16 + j;
            const unsigned u = keys[n];
            bool sel;
            if (u == T) { sel = ((int)rank < fneed); rank++; }
            else        { sel = (u > T); }
            keys[n] = sel ? 1u : 0u;
        }
        __syncthreads();
    }

    // coalesced in-place write
    for (int j = 0; j < 16; ++j) {
        const int n = j * 256 + t;
        Y[(size_t)r * NF + n] = keys[n] ? yv[n] : 0.0f;
    }
}

// ---------------------------------------------------------------------------
extern "C" void kernel_launch(void* const* d_in, const int* in_sizes, int n_in,
                              void* d_out, int out_size, void* d_ws, size_t ws_size,
                              hipStream_t stream)
{
    const float* x     = (const float*)d_in[0];
    const float* W     = (const float*)d_in[1];
    const float* b     = (const float*)d_in[2];
    const int*   wmask = (const int*)d_in[3];
    const float* duty  = (const float*)d_in[4];
    const int*   kp    = (const int*)d_in[5];
    float* out = (float*)d_out;

    double* dsum   = (double*)d_ws;          // [4096]
    double* dsqs   = dsum + NF;              // [4096]
    double* mean64 = dsqs + NF;              // [4096]
    double* rstd64 = mean64 + NF;            // [4096]
    double* boost64 = rstd64 + NF;           // [4096]
    float*  mean32 = (float*)(boost64 + NF); // [4096]
    float*  rstd32 = mean32 + NF;            // [4096]
    float*  boost32 = rstd32 + NF;           // [4096]

    hipLaunchKernelGGL(zero_ws, dim3(2 * NF / 256), dim3(256), 0, stream, dsum);
    hipLaunchKernelGGL(gemm_mfma_split, dim3(NF / 128, BATCH / 128), dim3(512), 0, stream,
                       x, W, wmask, b, out);
    hipLaunchKernelGGL(stats_partial, dim3(NF / 256, BATCH / 256), dim3(256), 0, stream,
                       out, dsum, dsqs);
    hipLaunchKernelGGL(stats_final, dim3(NF / 256), dim3(256), 0, stream,
                       dsum, dsqs, duty, kp,
                       mean64, rstd64, boost64, mean32, rstd32, boost32);
    hipLaunchKernelGGL(topk_kernel, dim3(BATCH), dim3(256), 0, stream,
                       mean32, rstd32, boost32, mean64, rstd64, boost64, kp,
                       x, W, wmask, b, out);
}

// Round 7
// 655.912 us; speedup vs baseline: 3.9734x; 1.1524x over previous
//
#include <hip/hip_runtime.h>

// Problem constants (fixed-shape: B=8192, IN=1024, N=4096, K=409)
#define BATCH 8192
#define INF   1024
#define NF    4096
#define BN_EPS 1e-5

typedef __attribute__((ext_vector_type(8))) short short8v;
typedef __attribute__((ext_vector_type(4))) float f32x4;

// ---------------------------------------------------------------------------
// Kernel 1: zero the f64 stats accumulators (2*4096 doubles)
// ---------------------------------------------------------------------------
__global__ void zero_ws(double* __restrict__ p) {
    p[blockIdx.x * 256 + threadIdx.x] = 0.0;
}

// ---------------------------------------------------------------------------
// Exact 3-way bf16 truncation split: x == bf16(h0)+bf16(h1)+bf16(h2) EXACTLY
// (f32 has 24 significand bits; h0/h1/h2 take bits 1-8 / 9-16 / 17-24).
// ---------------------------------------------------------------------------
__device__ __forceinline__ void split3(float x, ushort& h0, ushort& h1, ushort& h2) {
    const unsigned u0 = __float_as_uint(x) & 0xFFFF0000u;
    const float    r1 = x - __uint_as_float(u0);
    const unsigned u1 = __float_as_uint(r1) & 0xFFFF0000u;
    const float    r2 = r1 - __uint_as_float(u1);   // <=8 significant bits: bf16-exact
    h0 = (ushort)(u0 >> 16);
    h1 = (ushort)(u1 >> 16);
    h2 = (ushort)(__float_as_uint(r2) >> 16);
}

// ---------------------------------------------------------------------------
// Kernel 1b/1c: pre-split X and (masked) W into 3 bf16 planes in workspace.
// Each thread handles 8 consecutive floats; writes 3x short8v (16B coalesced).
// ---------------------------------------------------------------------------
__global__ __launch_bounds__(256) void split_x_kernel(
    const float* __restrict__ X, ushort* __restrict__ xs)
{
    const size_t base = ((size_t)blockIdx.x * 256 + threadIdx.x) * 8;
    const size_t LS = (size_t)BATCH * INF;
    const float4 v0 = *(const float4*)(X + base);
    const float4 v1 = *(const float4*)(X + base + 4);
    const float v[8] = {v0.x, v0.y, v0.z, v0.w, v1.x, v1.y, v1.z, v1.w};
    short8v s0, s1, s2;
#pragma unroll
    for (int i = 0; i < 8; ++i) {
        ushort h0, h1, h2;
        split3(v[i], h0, h1, h2);
        s0[i] = (short)h0; s1[i] = (short)h1; s2[i] = (short)h2;
    }
    *(short8v*)&xs[base]          = s0;
    *(short8v*)&xs[base + LS]     = s1;
    *(short8v*)&xs[base + 2 * LS] = s2;
}

__global__ __launch_bounds__(256) void split_w_kernel(
    const float* __restrict__ W, const int* __restrict__ Mk, ushort* __restrict__ wsp)
{
    const size_t base = ((size_t)blockIdx.x * 256 + threadIdx.x) * 8;
    const size_t LS = (size_t)NF * INF;
    const float4 v0 = *(const float4*)(W + base);
    const float4 v1 = *(const float4*)(W + base + 4);
    const int4   m0 = *(const int4*)(Mk + base);
    const int4   m1 = *(const int4*)(Mk + base + 4);
    const float v[8] = {v0.x * (float)m0.x, v0.y * (float)m0.y,
                        v0.z * (float)m0.z, v0.w * (float)m0.w,
                        v1.x * (float)m1.x, v1.y * (float)m1.y,
                        v1.z * (float)m1.z, v1.w * (float)m1.w};
    short8v s0, s1, s2;
#pragma unroll
    for (int i = 0; i < 8; ++i) {
        ushort h0, h1, h2;
        split3(v[i], h0, h1, h2);
        s0[i] = (short)h0; s1[i] = (short)h1; s2[i] = (short)h2;
    }
    *(short8v*)&wsp[base]          = s0;
    *(short8v*)&wsp[base + LS]     = s1;
    *(short8v*)&wsp[base + 2 * LS] = s2;
}

// ---------------------------------------------------------------------------
// Kernel 2 (fast path): masked GEMM via bf16 MFMA on PRE-SPLIT planes.
// 6 cross-products (00,01,10,02,11,20); dropped terms <= 2^-23|xw| -> sigma
// ~2e-8, below the passing config's MFMA rounding. f32 frag accs drained
// into f64 shadow every Kc=64. Tile 128x128, BK=32, 512 thr = 8 waves (4Mx2N),
// wave = 32x64 = 2x4 frags of mfma_f32_16x16x32_bf16.
// ---------------------------------------------------------------------------
__global__ __launch_bounds__(512) void gemm_mfma_pre(
    const ushort* __restrict__ Xs, const ushort* __restrict__ Wsp,
    const float* __restrict__ bias, float* __restrict__ Y)
{
    __shared__ __align__(16) ushort a0s[128 * 40];
    __shared__ __align__(16) ushort a1s[128 * 40];
    __shared__ __align__(16) ushort a2s[128 * 40];
    __shared__ __align__(16) ushort b0s[128 * 40];
    __shared__ __align__(16) ushort b1s[128 * 40];
    __shared__ __align__(16) ushort b2s[128 * 40];

    const size_t LSX = (size_t)BATCH * INF;
    const size_t LSW = (size_t)NF * INF;

    const int t = threadIdx.x;
    const int row0 = blockIdx.y * 128;
    const int col0 = blockIdx.x * 128;

    const int srow = t >> 2;          // 0..127
    const int skb  = (t & 3) * 8;     // 0,8,16,24

    const ushort* Xp = Xs  + (size_t)(row0 + srow) * INF + skb;
    const ushort* Wp = Wsp + (size_t)(col0 + srow) * INF + skb;

    const int l   = t & 63;
    const int l15 = l & 15;
    const int hi  = l >> 4;
    const int wid = t >> 6;
    const int wm  = wid >> 1;         // 0..3 : m-offset wm*32
    const int wn  = wid & 1;          // 0..1 : n-offset wn*64

    f32x4  acc[2][4];
    double sh[2][4][4];
#pragma unroll
    for (int mf = 0; mf < 2; ++mf)
#pragma unroll
        for (int nf = 0; nf < 4; ++nf) {
            acc[mf][nf] = (f32x4){0.f, 0.f, 0.f, 0.f};
#pragma unroll
            for (int r = 0; r < 4; ++r) sh[mf][nf][r] = 0.0;
        }

    // prefetch tile 0
    short8v pa0 = *(const short8v*)(Xp);
    short8v pa1 = *(const short8v*)(Xp + LSX);
    short8v pa2 = *(const short8v*)(Xp + 2 * LSX);
    short8v pb0 = *(const short8v*)(Wp);
    short8v pb1 = *(const short8v*)(Wp + LSW);
    short8v pb2 = *(const short8v*)(Wp + 2 * LSW);

    for (int k0 = 0; k0 < INF; k0 += 32) {
        __syncthreads();   // previous iteration's frag reads done
        const int off = srow * 40 + skb;
        *(short8v*)&a0s[off] = pa0;
        *(short8v*)&a1s[off] = pa1;
        *(short8v*)&a2s[off] = pa2;
        *(short8v*)&b0s[off] = pb0;
        *(short8v*)&b1s[off] = pb1;
        *(short8v*)&b2s[off] = pb2;
        __syncthreads();

        if (k0 + 32 < INF) {   // prefetch next tile; overlaps frag reads+MFMA
            const int kn = k0 + 32;
            pa0 = *(const short8v*)(Xp + kn);
            pa1 = *(const short8v*)(Xp + kn + LSX);
            pa2 = *(const short8v*)(Xp + kn + 2 * LSX);
            pb0 = *(const short8v*)(Wp + kn);
            pb1 = *(const short8v*)(Wp + kn + LSW);
            pb2 = *(const short8v*)(Wp + kn + 2 * LSW);
        }

        short8v A[2][3], B[4][3];
#pragma unroll
        for (int mf = 0; mf < 2; ++mf) {
            const int roff = (wm * 32 + mf * 16 + l15) * 40 + hi * 8;
            A[mf][0] = *(const short8v*)&a0s[roff];
            A[mf][1] = *(const short8v*)&a1s[roff];
            A[mf][2] = *(const short8v*)&a2s[roff];
        }
#pragma unroll
        for (int nf = 0; nf < 4; ++nf) {
            const int roff = (wn * 64 + nf * 16 + l15) * 40 + hi * 8;
            B[nf][0] = *(const short8v*)&b0s[roff];
            B[nf][1] = *(const short8v*)&b1s[roff];
            B[nf][2] = *(const short8v*)&b2s[roff];
        }

        // 6 cross-products: levels 0+0,0+1,1+0,0+2,1+1,2+0
#pragma unroll
        for (int mf = 0; mf < 2; ++mf)
#pragma unroll
            for (int nf = 0; nf < 4; ++nf) {
                f32x4 c = acc[mf][nf];
                c = __builtin_amdgcn_mfma_f32_16x16x32_bf16(A[mf][0], B[nf][0], c, 0, 0, 0);
                c = __builtin_amdgcn_mfma_f32_16x16x32_bf16(A[mf][0], B[nf][1], c, 0, 0, 0);
                c = __builtin_amdgcn_mfma_f32_16x16x32_bf16(A[mf][1], B[nf][0], c, 0, 0, 0);
                c = __builtin_amdgcn_mfma_f32_16x16x32_bf16(A[mf][0], B[nf][2], c, 0, 0, 0);
                c = __builtin_amdgcn_mfma_f32_16x16x32_bf16(A[mf][1], B[nf][1], c, 0, 0, 0);
                c = __builtin_amdgcn_mfma_f32_16x16x32_bf16(A[mf][2], B[nf][0], c, 0, 0, 0);
                acc[mf][nf] = c;
            }

        if (k0 & 32) {   // drain f32 frag accs into f64 shadow every Kc=64
#pragma unroll
            for (int mf = 0; mf < 2; ++mf)
#pragma unroll
                for (int nf = 0; nf < 4; ++nf) {
#pragma unroll
                    for (int r = 0; r < 4; ++r) sh[mf][nf][r] += (double)acc[mf][nf][r];
                    acc[mf][nf] = (f32x4){0.f, 0.f, 0.f, 0.f};
                }
        }
    }

    // epilogue: add bias in f64, store f32
#pragma unroll
    for (int mf = 0; mf < 2; ++mf)
#pragma unroll
        for (int nf = 0; nf < 4; ++nf) {
            const int col = col0 + wn * 64 + nf * 16 + l15;
            const double bb = (double)bias[col];
#pragma unroll
            for (int r = 0; r < 4; ++r) {
                const int row = row0 + wm * 32 + mf * 16 + hi * 4 + r;
                Y[(size_t)row * NF + col] = (float)(sh[mf][nf][r] + bb);
            }
        }
}

// ---------------------------------------------------------------------------
// Kernel 2 (fallback, ws too small): in-kernel split, 6 products.
// ---------------------------------------------------------------------------
__global__ __launch_bounds__(512) void gemm_mfma_split(
    const float* __restrict__ X, const float* __restrict__ W,
    const int* __restrict__ Mk, const float* __restrict__ bias,
    float* __restrict__ Y)
{
    __shared__ __align__(16) ushort a0s[128 * 40];
    __shared__ __align__(16) ushort a1s[128 * 40];
    __shared__ __align__(16) ushort a2s[128 * 40];
    __shared__ __align__(16) ushort b0s[128 * 40];
    __shared__ __align__(16) ushort b1s[128 * 40];
    __shared__ __align__(16) ushort b2s[128 * 40];

    const int t = threadIdx.x;
    const int row0 = blockIdx.y * 128;
    const int col0 = blockIdx.x * 128;
    const int srow = t >> 2;
    const int skb  = (t & 3) * 8;

    const float* Xp = X + (size_t)(row0 + srow) * INF + skb;
    const float* Wp = W + (size_t)(col0 + srow) * INF + skb;
    const int*   Mp = Mk + (size_t)(col0 + srow) * INF + skb;

    const int l   = t & 63;
    const int l15 = l & 15;
    const int hi  = l >> 4;
    const int wid = t >> 6;
    const int wm  = wid >> 1;
    const int wn  = wid & 1;

    f32x4  acc[2][4];
    double sh[2][4][4];
#pragma unroll
    for (int mf = 0; mf < 2; ++mf)
#pragma unroll
        for (int nf = 0; nf < 4; ++nf) {
            acc[mf][nf] = (f32x4){0.f, 0.f, 0.f, 0.f};
#pragma unroll
            for (int r = 0; r < 4; ++r) sh[mf][nf][r] = 0.0;
        }

    float4 xA0 = *(const float4*)(Xp);
    float4 xA1 = *(const float4*)(Xp + 4);
    float4 wB0 = *(const float4*)(Wp);
    float4 wB1 = *(const float4*)(Wp + 4);
    int4   mB0 = *(const int4*)(Mp);
    int4   mB1 = *(const int4*)(Mp + 4);

    for (int k0 = 0; k0 < INF; k0 += 32) {
        __syncthreads();
        {
            const float v[8] = {xA0.x, xA0.y, xA0.z, xA0.w, xA1.x, xA1.y, xA1.z, xA1.w};
            short8v s0, s1, s2;
#pragma unroll
            for (int i = 0; i < 8; ++i) {
                ushort h0, h1, h2;
                split3(v[i], h0, h1, h2);
                s0[i] = (short)h0; s1[i] = (short)h1; s2[i] = (short)h2;
            }
            const int off = srow * 40 + skb;
            *(short8v*)&a0s[off] = s0;
            *(short8v*)&a1s[off] = s1;
            *(short8v*)&a2s[off] = s2;
        }
        {
            const float wv[8] = {wB0.x * (float)mB0.x, wB0.y * (float)mB0.y,
                                 wB0.z * (float)mB0.z, wB0.w * (float)mB0.w,
                                 wB1.x * (float)mB1.x, wB1.y * (float)mB1.y,
                                 wB1.z * (float)mB1.z, wB1.w * (float)mB1.w};
            short8v s0, s1, s2;
#pragma unroll
            for (int i = 0; i < 8; ++i) {
                ushort h0, h1, h2;
                split3(wv[i], h0, h1, h2);
                s0[i] = (short)h0; s1[i] = (short)h1; s2[i] = (short)h2;
            }
            const int off = srow * 40 + skb;
            *(short8v*)&b0s[off] = s0;
            *(short8v*)&b1s[off] = s1;
            *(short8v*)&b2s[off] = s2;
        }
        __syncthreads();

        if (k0 + 32 < INF) {
            const int kn = k0 + 32;
            xA0 = *(const float4*)(Xp + kn);
            xA1 = *(const float4*)(Xp + kn + 4);
            wB0 = *(const float4*)(Wp + kn);
            wB1 = *(const float4*)(Wp + kn + 4);
            mB0 = *(const int4*)(Mp + kn);
            mB1 = *(const int4*)(Mp + kn + 4);
        }

        short8v A[2][3], B[4][3];
#pragma unroll
        for (int mf = 0; mf < 2; ++mf) {
            const int roff = (wm * 32 + mf * 16 + l15) * 40 + hi * 8;
            A[mf][0] = *(const short8v*)&a0s[roff];
            A[mf][1] = *(const short8v*)&a1s[roff];
            A[mf][2] = *(const short8v*)&a2s[roff];
        }
#pragma unroll
        for (int nf = 0; nf < 4; ++nf) {
            const int roff = (wn * 64 + nf * 16 + l15) * 40 + hi * 8;
            B[nf][0] = *(const short8v*)&b0s[roff];
            B[nf][1] = *(const short8v*)&b1s[roff];
            B[nf][2] = *(const short8v*)&b2s[roff];
        }

#pragma unroll
        for (int mf = 0; mf < 2; ++mf)
#pragma unroll
            for (int nf = 0; nf < 4; ++nf) {
                f32x4 c = acc[mf][nf];
                c = __builtin_amdgcn_mfma_f32_16x16x32_bf16(A[mf][0], B[nf][0], c, 0, 0, 0);
                c = __builtin_amdgcn_mfma_f32_16x16x32_bf16(A[mf][0], B[nf][1], c, 0, 0, 0);
                c = __builtin_amdgcn_mfma_f32_16x16x32_bf16(A[mf][1], B[nf][0], c, 0, 0, 0);
                c = __builtin_amdgcn_mfma_f32_16x16x32_bf16(A[mf][0], B[nf][2], c, 0, 0, 0);
                c = __builtin_amdgcn_mfma_f32_16x16x32_bf16(A[mf][1], B[nf][1], c, 0, 0, 0);
                c = __builtin_amdgcn_mfma_f32_16x16x32_bf16(A[mf][2], B[nf][0], c, 0, 0, 0);
                acc[mf][nf] = c;
            }

        if (k0 & 32) {
#pragma unroll
            for (int mf = 0; mf < 2; ++mf)
#pragma unroll
                for (int nf = 0; nf < 4; ++nf) {
#pragma unroll
                    for (int r = 0; r < 4; ++r) sh[mf][nf][r] += (double)acc[mf][nf][r];
                    acc[mf][nf] = (f32x4){0.f, 0.f, 0.f, 0.f};
                }
        }
    }

#pragma unroll
    for (int mf = 0; mf < 2; ++mf)
#pragma unroll
        for (int nf = 0; nf < 4; ++nf) {
            const int col = col0 + wn * 64 + nf * 16 + l15;
            const double bb = (double)bias[col];
#pragma unroll
            for (int r = 0; r < 4; ++r) {
                const int row = row0 + wm * 32 + mf * 16 + hi * 4 + r;
                Y[(size_t)row * NF + col] = (float)(sh[mf][nf][r] + bb);
            }
        }
}

// ---------------------------------------------------------------------------
// Kernel 3: per-column partial sums (f64) over 256-row chunks
// ---------------------------------------------------------------------------
__global__ __launch_bounds__(256) void stats_partial(
    const float* __restrict__ Y, double* __restrict__ dsum, double* __restrict__ dsqs)
{
    const int col = blockIdx.x * 256 + threadIdx.x;
    const int r0  = blockIdx.y * 256;
    double s = 0.0, ss = 0.0;
    for (int i = 0; i < 256; ++i) {
        const float v = Y[(size_t)(r0 + i) * NF + col];
        s  += (double)v;
        ss += (double)v * (double)v;
    }
    atomicAdd(&dsum[col], s);
    atomicAdd(&dsqs[col], ss);
}

// ---------------------------------------------------------------------------
// Kernel 4: finalize mean / rstd / boost (f64 + f32 copies)
// ---------------------------------------------------------------------------
__global__ __launch_bounds__(256) void stats_final(
    const double* __restrict__ dsum, const double* __restrict__ dsqs,
    const float* __restrict__ duty, const int* __restrict__ kp,
    double* __restrict__ mean64, double* __restrict__ rstd64, double* __restrict__ boost64,
    float* __restrict__ mean32, float* __restrict__ rstd32, float* __restrict__ boost32)
{
    const int c = blockIdx.x * 256 + threadIdx.x;
    const double m   = dsum[c] / (double)BATCH;
    const double var = dsqs[c] / (double)BATCH - m * m;
    const double rs  = 1.0 / sqrt(var + (double)BN_EPS);
    const double td  = (double)(*kp) / (double)NF;
    const double bf  = exp(td - (double)duty[c]);
    mean64[c] = m;  rstd64[c] = rs;  boost64[c] = bf;
    mean32[c] = (float)m; rstd32[c] = (float)rs; boost32[c] = (float)bf;
}

// ---------------------------------------------------------------------------
// Kernel 5: per-row BN-apply + boosted top-k (radix select, f32) with f64
// band refinement near the cutoff + scatter (in place). One block per row.
// ---------------------------------------------------------------------------
#define BAND 1e-4f
#define MAXCAND 64

__global__ __launch_bounds__(256) void topk_kernel(
    const float* __restrict__ mean32, const float* __restrict__ rstd32,
    const float* __restrict__ boost32,
    const double* __restrict__ mean64, const double* __restrict__ rstd64,
    const double* __restrict__ boost64,
    const int* __restrict__ kp,
    const float* __restrict__ X, const float* __restrict__ W,
    const int* __restrict__ Mk, const float* __restrict__ bias,
    float* __restrict__ Y)
{
    __shared__ float    yv[NF];
    __shared__ unsigned keys[NF];
    __shared__ unsigned hist[256];
    __shared__ unsigned scan[256];
    __shared__ unsigned s_bin, s_below;
    __shared__ double   red[256];
    __shared__ int      s_ncand, s_H;
    __shared__ int      cand_idx[MAXCAND];
    __shared__ double   cand_val[MAXCAND];
    __shared__ unsigned char cand_pick[MAXCAND];

    const int r = blockIdx.x;
    const int t = threadIdx.x;
    const int K = *kp;

    for (int j = 0; j < 16; ++j) {
        const int n = j * 256 + t;
        const float v   = Y[(size_t)r * NF + n];
        const float ybn = (v - mean32[n]) * rstd32[n];
        yv[n] = ybn;
        const float bst = ybn * boost32[n];
        unsigned u = __float_as_uint(bst);
        u ^= (u & 0x80000000u) ? 0xFFFFFFFFu : 0x80000000u;
        keys[n] = u;
    }
    __syncthreads();

    unsigned curval = 0u, curmask = 0u;
    int remaining = K;
    for (int pass = 3; pass >= 0; --pass) {
        const int sh = pass * 8;
        hist[t] = 0u;
        __syncthreads();
        for (int j = 0; j < 16; ++j) {
            const unsigned u = keys[j * 256 + t];
            if ((u & curmask) == curval)
                atomicAdd(&hist[(u >> sh) & 255u], 1u);
        }
        __syncthreads();
        scan[t] = hist[t];
        __syncthreads();
        for (int off = 1; off < 256; off <<= 1) {
            const unsigned add = (t + off < 256) ? scan[t + off] : 0u;
            __syncthreads();
            scan[t] += add;
            __syncthreads();
        }
        if (scan[t] >= (unsigned)remaining &&
            (t == 255 || scan[t + 1] < (unsigned)remaining)) {
            s_bin = (unsigned)t;
            s_below = (t == 255) ? 0u : scan[t + 1];
        }
        __syncthreads();
        curval |= (s_bin << sh);
        curmask |= (255u << sh);
        remaining -= (int)s_below;
        __syncthreads();
    }

    const unsigned T = curval;
    const unsigned vT = (T & 0x80000000u) ? (T ^ 0x80000000u) : ~T;
    const float cut32 = __uint_as_float(vT);
    const float cutHi = cut32 + BAND;
    const float cutLo = cut32 - BAND;

    if (t == 0) { s_ncand = 0; s_H = 0; }
    __syncthreads();
    int locH = 0;
    for (int j = 0; j < 16; ++j) {
        const int n = j * 256 + t;
        const float b = yv[n] * boost32[n];
        if (b > cutHi) {
            locH++;
        } else if (b >= cutLo) {
            const int slot = atomicAdd(&s_ncand, 1);
            if (slot < MAXCAND) cand_idx[slot] = n;
        }
    }
    atomicAdd(&s_H, locH);
    __syncthreads();
    const int H = s_H;
    const bool overflow = (s_ncand > MAXCAND);
    const int ncand = overflow ? MAXCAND : s_ncand;
    int need = K - H;
    if (need < 0) need = 0;

    if (!overflow) {
        for (int c = 0; c < ncand; ++c) {
            const int n = cand_idx[c];
            const float* xr = X + (size_t)r * INF;
            const float* wn = W + (size_t)n * INF;
            const int*   mn = Mk + (size_t)n * INF;
            double s = 0.0;
            for (int i = t; i < INF; i += 256)
                s += (double)xr[i] * (double)(wn[i] * (float)mn[i]);
            red[t] = s;
            __syncthreads();
            for (int off = 128; off > 0; off >>= 1) {
                if (t < off) red[t] += red[t + off];
                __syncthreads();
            }
            if (t == 0) {
                const double y64 = red[0] + (double)bias[n];
                cand_val[c] = (y64 - mean64[n]) * rstd64[n] * boost64[n];
                cand_pick[c] = 0;
            }
            __syncthreads();
        }
        if (t == 0) {
            for (int p = 0; p < need; ++p) {
                int best = -1;
                for (int c = 0; c < ncand; ++c) {
                    if (cand_pick[c]) continue;
                    if (best < 0 || cand_val[c] > cand_val[best] ||
                        (cand_val[c] == cand_val[best] && cand_idx[c] < cand_idx[best]))
                        best = c;
                }
                if (best < 0) break;
                cand_pick[best] = 1;
            }
        }
        __syncthreads();
        for (int j = 0; j < 16; ++j) {
            const int n = j * 256 + t;
            const float b = yv[n] * boost32[n];
            keys[n] = (b > cutHi) ? 1u : 0u;
        }
        __syncthreads();
        if (t < ncand && cand_pick[t]) keys[cand_idx[t]] = 1u;
        __syncthreads();
    } else {
        const int fneed = remaining;
        unsigned cnt = 0u;
        for (int j = 0; j < 16; ++j) cnt += (keys[t * 16 + j] == T) ? 1u : 0u;
        scan[t] = cnt;
        __syncthreads();
        for (int off = 1; off < 256; off <<= 1) {
            const unsigned add = (t >= off) ? scan[t - off] : 0u;
            __syncthreads();
            scan[t] += add;
            __syncthreads();
        }
        unsigned rank = scan[t] - cnt;
        for (int j = 0; j < 16; ++j) {
            const int n = t * 16 + j;
            const unsigned u = keys[n];
            bool sel;
            if (u == T) { sel = ((int)rank < fneed); rank++; }
            else        { sel = (u > T); }
            keys[n] = sel ? 1u : 0u;
        }
        __syncthreads();
    }

    for (int j = 0; j < 16; ++j) {
        const int n = j * 256 + t;
        Y[(size_t)r * NF + n] = keys[n] ? yv[n] : 0.0f;
    }
}

// ---------------------------------------------------------------------------
extern "C" void kernel_launch(void* const* d_in, const int* in_sizes, int n_in,
                              void* d_out, int out_size, void* d_ws, size_t ws_size,
                              hipStream_t stream)
{
    const float* x     = (const float*)d_in[0];
    const float* W     = (const float*)d_in[1];
    const float* b     = (const float*)d_in[2];
    const int*   wmask = (const int*)d_in[3];
    const float* duty  = (const float*)d_in[4];
    const int*   kp    = (const int*)d_in[5];
    float* out = (float*)d_out;

    const size_t SPLIT_X_ELTS = (size_t)3 * BATCH * INF;   // ushorts
    const size_t SPLIT_W_ELTS = (size_t)3 * NF * INF;
    const size_t STATS_BYTES  = (size_t)5 * NF * sizeof(double) + (size_t)3 * NF * sizeof(float);
    const size_t NEED_FAST    = (SPLIT_X_ELTS + SPLIT_W_ELTS) * sizeof(ushort) + STATS_BYTES;
    const bool fast = (ws_size >= NEED_FAST);

    ushort* xs  = (ushort*)d_ws;
    ushort* wsp = xs + SPLIT_X_ELTS;
    char* statbase = fast ? (char*)(wsp + SPLIT_W_ELTS) : (char*)d_ws;

    double* dsum    = (double*)statbase;     // [4096]
    double* dsqs    = dsum + NF;             // [4096]
    double* mean64  = dsqs + NF;             // [4096]
    double* rstd64  = mean64 + NF;           // [4096]
    double* boost64 = rstd64 + NF;           // [4096]
    float*  mean32  = (float*)(boost64 + NF);
    float*  rstd32  = mean32 + NF;
    float*  boost32 = rstd32 + NF;

    hipLaunchKernelGGL(zero_ws, dim3(2 * NF / 256), dim3(256), 0, stream, dsum);

    if (fast) {
        hipLaunchKernelGGL(split_x_kernel, dim3(BATCH * INF / 8 / 256), dim3(256), 0, stream,
                           x, xs);
        hipLaunchKernelGGL(split_w_kernel, dim3(NF * INF / 8 / 256), dim3(256), 0, stream,
                           W, wmask, wsp);
        hipLaunchKernelGGL(gemm_mfma_pre, dim3(NF / 128, BATCH / 128), dim3(512), 0, stream,
                           xs, wsp, b, out);
    } else {
        hipLaunchKernelGGL(gemm_mfma_split, dim3(NF / 128, BATCH / 128), dim3(512), 0, stream,
                           x, W, wmask, b, out);
    }

    hipLaunchKernelGGL(stats_partial, dim3(NF / 256, BATCH / 256), dim3(256), 0, stream,
                       out, dsum, dsqs);
    hipLaunchKernelGGL(stats_final, dim3(NF / 256), dim3(256), 0, stream,
                       dsum, dsqs, duty, kp,
                       mean64, rstd64, boost64, mean32, rstd32, boost32);
    hipLaunchKernelGGL(topk_kernel, dim3(BATCH), dim3(256), 0, stream,
                       mean32, rstd32, boost32, mean64, rstd64, boost64, kp,
                       x, W, wmask, b, out);
}